// Round 8
// baseline (704.946 us; speedup 1.0000x reference)
//
#include <hip/hip_runtime.h>
#include <stdint.h>

typedef unsigned short ushort_t;

#define NN    2048
#define DIMC  256
#define H1    1030
#define MD    64
#define NROWS 8192

// P/Q row stride (bf16 elems), padded so vector loads never cross rows
#define HP       1040

// edge MFMA tiling (registers only, no LDS): K padded to 33*32
#define KPAD     1056
#define NKS      33

// pq GEMM: N = 2*1030 = 2060, padded to 2112 = 33*64
#define NPQ      2060
#define NPQP     2112
#define KN1      320         // node1 K = 256 + 64
#define KN2      512         // node2 K

// stage1 role sizes
#define ADJ_BLKS 2048
#define PREP_TOT (NPQP*DIMC + 512*KN1 + 256*KN2 + MD*KPAD + 3*HP + NROWS*DIMC)  // 3,003,440
#define MACCZ    (NROWS*MD/4)     // 131072 float4
#define COORSZ   (24576/4)        // 6144 float4
// stage4 role sizes
#define N4_BLKS  256              // node blocks (32 rows each)
#define FCOPY4   (33554432/4)     // 8,388,608 float4 -> 32768 copy blocks

typedef __bf16 bf16x8 __attribute__((ext_vector_type(8)));
typedef float  f32x4  __attribute__((ext_vector_type(4)));
typedef ushort_t u16x8 __attribute__((ext_vector_type(8)));

__device__ __forceinline__ float bfu2f(ushort_t u){ union{unsigned u; float f;} v; v.u = ((unsigned)u)<<16; return v.f; }
__device__ __forceinline__ ushort_t f2bfu(float f){ union{float f; unsigned u;} v; v.f=f; unsigned r = (v.u + 0x7FFFu + ((v.u>>16)&1u))>>16; return (ushort_t)r; }
__device__ __forceinline__ float siluf(float x){ return x / (1.0f + __expf(-x)); }
__device__ __forceinline__ void split_hilo(float v, ushort_t& hi, ushort_t& lo){
    hi = f2bfu(v);
    lo = f2bfu(v - bfu2f(hi));
}

// ================= stage1: adj scan + all prep packs + macc zero + coors copy ===============
__global__ void stage1(const int* __restrict__ adj, const int* __restrict__ mask,
                       const float* __restrict__ coors,
                       const float* __restrict__ eW1, const float* __restrict__ nW1,
                       const float* __restrict__ nW2, const float* __restrict__ eW2,
                       const float* __restrict__ emb,
                       float* __restrict__ out_adj, float* __restrict__ out_mask,
                       float* __restrict__ out_coors,
                       int* __restrict__ pairs, int* __restrict__ counter,
                       ushort_t* __restrict__ Wpq_h, ushort_t* __restrict__ Wpq_l,
                       ushort_t* __restrict__ W1T_h, ushort_t* __restrict__ W1T_l,
                       ushort_t* __restrict__ NW2T_h, ushort_t* __restrict__ NW2T_l,
                       ushort_t* __restrict__ W2T, float* __restrict__ wt4,
                       ushort_t* __restrict__ Ah, ushort_t* __restrict__ Al,
                       float* __restrict__ macc)
{
    if (blockIdx.x < ADJ_BLKS) {
        // ---- adj role: 4 rows/block, int4-vectorized, pair emission ----
        const int w = threadIdx.x >> 6, lane = threadIdx.x & 63;
        const int row = blockIdx.x*4 + w;
        const int b = row >> 11, i = row & (NN-1);
        __shared__ int nbrs[4][15];
        int total = 0;
        const size_t rbase = (size_t)row * NN;
        const int4* arow = (const int4*)(adj + rbase);
        float4* orow = (float4*)(out_adj + rbase);
        for (int c = 0; c < NN/256; c++) {
            int4 v = arow[c*64 + lane];
            int j0 = c*256 + lane*4;
            float4 ov; ov.x = v.x?1.f:0.f; ov.y = v.y?1.f:0.f; ov.z = v.z?1.f:0.f; ov.w = v.w?1.f:0.f;
            orow[c*64 + lane] = ov;
            bool p0 = v.x && (j0   != i);
            bool p1 = v.y && (j0+1 != i);
            bool p2 = v.z && (j0+2 != i);
            bool p3 = v.w && (j0+3 != i);
            unsigned long long b0 = __ballot(p0), b1 = __ballot(p1), b2 = __ballot(p2), b3 = __ballot(p3);
            unsigned long long below = (1ull<<lane)-1ull;
            int slot = total + __popcll(b0&below)+__popcll(b1&below)+__popcll(b2&below)+__popcll(b3&below);
            if (p0 && slot < 15) nbrs[w][slot] = j0;
            slot += p0;
            if (p1 && slot < 15) nbrs[w][slot] = j0+1;
            slot += p1;
            if (p2 && slot < 15) nbrs[w][slot] = j0+2;
            slot += p2;
            if (p3 && slot < 15) nbrs[w][slot] = j0+3;
            total += __popcll(b0)+__popcll(b1)+__popcll(b2)+__popcll(b3);
        }
        int cnt = total < 15 ? total : 15;
        const int mv = mask[row];
        if (lane == 0) out_mask[row] = mv ? 1.0f : 0.0f;
        if (mv != 0) {
            int jl = (lane < cnt) ? nbrs[w][lane] : 0;
            bool ok = (lane < cnt) && (mask[b*NN + jl] != 0);
            unsigned long long bm = __ballot(ok);
            int npair = 1 + __popcll(bm);
            int basep = 0;
            if (lane == 0) basep = atomicAdd(counter, npair);
            basep = __shfl(basep, 0);
            if (lane == 0) pairs[basep] = (row << 16) | i;      // self pair
            if (ok) {
                int pos = basep + 1 + __popcll(bm & ((1ull<<lane)-1ull));
                pairs[pos] = (row << 16) | jl;
            }
        }
        return;
    }
    // ---- flat roles ----
    int t = (blockIdx.x - ADJ_BLKS)*256 + threadIdx.x;
    if (t < NPQP*DIMC) {            // Wpq[n][k]
        int n = t >> 8, k = t & 255;
        float v = 0.f;
        if (n < H1) v = eW1[(size_t)k*H1 + n];
        else if (n < NPQ) v = eW1[(size_t)(256+k)*H1 + (n - H1)];
        ushort_t hi, lo; split_hilo(v, hi, lo);
        Wpq_h[t] = hi; Wpq_l[t] = lo;
        return;
    }
    t -= NPQP*DIMC;
    if (t < 512*KN1) {              // W1T[n][k] from nW1[k][n]
        int n = t / KN1, k = t - n*KN1;
        ushort_t hi, lo; split_hilo(nW1[(size_t)k*512 + n], hi, lo);
        W1T_h[t] = hi; W1T_l[t] = lo;
        return;
    }
    t -= 512*KN1;
    if (t < 256*KN2) {              // NW2T[n][k] from nW2[k][n]
        int n = t >> 9, k = t & 511;
        ushort_t hi, lo; split_hilo(nW2[(size_t)k*256 + n], hi, lo);
        NW2T_h[t] = hi; NW2T_l[t] = lo;
        return;
    }
    t -= 256*KN2;
    if (t < MD*KPAD) {              // edge W2T[n][k] bf16, zero pad k>=H1
        int n = t / KPAD, k = t - n*KPAD;
        W2T[t] = f2bfu((k < H1) ? eW2[(size_t)k*MD + n] : 0.0f);
        return;
    }
    t -= MD*KPAD;
    if (t < 3*HP) {                 // wt4[c][k]: eW1 rows 512..514, zero pad k>=H1
        int c = t / HP, k = t - c*HP;
        wt4[t] = (k < H1) ? eW1[(size_t)(512+c)*H1 + k] : 0.f;
        return;
    }
    t -= 3*HP;
    if (t < NROWS*DIMC) {           // emb pack -> Aep hi/lo rows [r][0..256)
        int r = t >> 8, k = t & 255;
        ushort_t hi, lo; split_hilo(emb[t], hi, lo);
        Ah[(size_t)r*KN1 + k] = hi; Al[(size_t)r*KN1 + k] = lo;
        return;
    }
    t -= NROWS*DIMC;
    if (t < MACCZ) {                // macc zero (float4)
        float4 z; z.x = z.y = z.z = z.w = 0.f;
        ((float4*)macc)[t] = z;
        return;
    }
    t -= MACCZ;
    if (t < COORSZ) {               // coors passthrough (float4)
        ((float4*)out_coors)[t] = ((const float4*)coors)[t];
    }
}

// ================= MFMA 32x64 tile per wave: C[32][64] += A[32][K] * B[64][K]^T ===========
template<int K>
__device__ __forceinline__ void mfma_tile2(const ushort_t* __restrict__ Ah, const ushort_t* __restrict__ Al, int sA,
                                           const ushort_t* __restrict__ Bh, const ushort_t* __restrict__ Bl, int sB,
                                           int lane, f32x4 (&acc)[2][4])
{
    const int m16 = lane & 15, kg = lane >> 4;
    const ushort_t* a0h = Ah + (size_t)m16*sA + kg*8;
    const ushort_t* a0l = Al + (size_t)m16*sA + kg*8;
    const ushort_t* a1h = a0h + (size_t)16*sA;
    const ushort_t* a1l = a0l + (size_t)16*sA;
    const ushort_t* brh = Bh + (size_t)m16*sB + kg*8;
    const ushort_t* brl = Bl + (size_t)m16*sB + kg*8;
#pragma unroll 4
    for (int ks = 0; ks < K/32; ks++) {
        bf16x8 a0h_ = *reinterpret_cast<const bf16x8*>(a0h + ks*32);
        bf16x8 a0l_ = *reinterpret_cast<const bf16x8*>(a0l + ks*32);
        bf16x8 a1h_ = *reinterpret_cast<const bf16x8*>(a1h + ks*32);
        bf16x8 a1l_ = *reinterpret_cast<const bf16x8*>(a1l + ks*32);
#pragma unroll
        for (int nf = 0; nf < 4; nf++) {
            bf16x8 bh = *reinterpret_cast<const bf16x8*>(brh + (size_t)(nf*16)*sB + ks*32);
            bf16x8 bl = *reinterpret_cast<const bf16x8*>(brl + (size_t)(nf*16)*sB + ks*32);
            acc[0][nf] = __builtin_amdgcn_mfma_f32_16x16x32_bf16(a0h_, bh, acc[0][nf], 0, 0, 0);
            acc[0][nf] = __builtin_amdgcn_mfma_f32_16x16x32_bf16(a0h_, bl, acc[0][nf], 0, 0, 0);
            acc[0][nf] = __builtin_amdgcn_mfma_f32_16x16x32_bf16(a0l_, bh, acc[0][nf], 0, 0, 0);
            acc[1][nf] = __builtin_amdgcn_mfma_f32_16x16x32_bf16(a1h_, bh, acc[1][nf], 0, 0, 0);
            acc[1][nf] = __builtin_amdgcn_mfma_f32_16x16x32_bf16(a1h_, bl, acc[1][nf], 0, 0, 0);
            acc[1][nf] = __builtin_amdgcn_mfma_f32_16x16x32_bf16(a1l_, bh, acc[1][nf], 0, 0, 0);
        }
    }
}

// ---------------- P/Q via MFMA (eb1 folded into P at epilogue) ----------------
__global__ __launch_bounds__(256)
void gemm_pq_mfma(const ushort_t* __restrict__ Aeph, const ushort_t* __restrict__ Aepl,
                  const ushort_t* __restrict__ Wh, const ushort_t* __restrict__ Wl,
                  const float* __restrict__ eb1,
                  ushort_t* __restrict__ Pb, ushort_t* __restrict__ Qb)
{
    const int lane = threadIdx.x & 63, w = threadIdx.x >> 6;
    const int rowBase = blockIdx.x*128 + w*32;
    const int colBase = blockIdx.y*64;
    f32x4 acc[2][4] = {{{0,0,0,0},{0,0,0,0},{0,0,0,0},{0,0,0,0}},
                       {{0,0,0,0},{0,0,0,0},{0,0,0,0},{0,0,0,0}}};
    mfma_tile2<DIMC>(Aeph + (size_t)rowBase*KN1, Aepl + (size_t)rowBase*KN1, KN1,
                     Wh + (size_t)colBase*DIMC, Wl + (size_t)colBase*DIMC, DIMC, lane, acc);
    const int m16 = lane & 15, kg = lane >> 4;
#pragma unroll
    for (int tt = 0; tt < 2; tt++) {
#pragma unroll
        for (int nf = 0; nf < 4; nf++) {
#pragma unroll
            for (int r = 0; r < 4; r++) {
                int row = rowBase + tt*16 + kg*4 + r;
                int n = colBase + nf*16 + m16;
                if (n < H1) {
                    Pb[(size_t)row*HP + n] = f2bfu(acc[tt][nf][r] + eb1[n]);
                } else if (n < NPQ) {
                    Qb[(size_t)row*HP + (n - H1)] = f2bfu(acc[tt][nf][r]);
                }
            }
        }
    }
}

// ---------------- edge MLP: registers only, no LDS, no barriers ----------------
__global__ __launch_bounds__(256)
void edge_mfma(const int* __restrict__ pairs, const int* __restrict__ counter,
               const ushort_t* __restrict__ P, const ushort_t* __restrict__ Q,
               const float* __restrict__ coors, const float* __restrict__ feat,
               const float* __restrict__ wt4,
               const ushort_t* __restrict__ W2T, const float* __restrict__ eb2,
               float* __restrict__ macc)
{
    const int np = counter[0];
    const int lane = threadIdx.x & 63;
    const int w = threadIdx.x >> 6;
    const int wbase = blockIdx.x*64 + w*16;
    if (wbase >= np) return;
    const int m16 = lane & 15, kg = lane >> 4;

    const int pidx = wbase + m16;
    const int e = pairs[(pidx < np) ? pidx : wbase];
    const int row = e >> 16, j = e & 0xFFFF;
    const int jr = ((row >> 11) << 11) + j;
    const float dx = coors[row*3+0] - coors[jr*3+0];
    const float dy = coors[row*3+1] - coors[jr*3+1];
    const float dz = coors[row*3+2] - coors[jr*3+2];
    const float d  = dx*dx + dy*dy + dz*dz;
    const size_t fo = ((size_t)row*NN + j)*2;
    const float f0 = feat[fo], f1 = feat[fo+1];
    const ushort_t* Prow = P + (size_t)row*HP;
    const ushort_t* Qrow = Q + (size_t)jr*HP;
    const float* w512 = wt4;
    const float* w513 = wt4 + HP;
    const float* w514 = wt4 + 2*HP;
    const int kb = kg*8;

    f32x4 acc[4] = {{0,0,0,0},{0,0,0,0},{0,0,0,0},{0,0,0,0}};

    for (int ks = 0; ks < NKS; ks++) {
        const int k0 = ks*32 + kb;
        u16x8 hv = {0,0,0,0,0,0,0,0};
        u16x8 lv = {0,0,0,0,0,0,0,0};
        if (k0 < H1) {
            u16x8 pv8 = *reinterpret_cast<const u16x8*>(Prow + k0);
            u16x8 qv8 = *reinterpret_cast<const u16x8*>(Qrow + k0);
            f32x4 wa0 = *reinterpret_cast<const f32x4*>(w512 + k0);
            f32x4 wa1 = *reinterpret_cast<const f32x4*>(w512 + k0 + 4);
            f32x4 wb0 = *reinterpret_cast<const f32x4*>(w513 + k0);
            f32x4 wb1 = *reinterpret_cast<const f32x4*>(w513 + k0 + 4);
            f32x4 wc0 = *reinterpret_cast<const f32x4*>(w514 + k0);
            f32x4 wc1 = *reinterpret_cast<const f32x4*>(w514 + k0 + 4);
#pragma unroll
            for (int ee = 0; ee < 8; ee++) {
                float va = (ee < 4) ? wa0[ee] : wa1[ee-4];
                float vb = (ee < 4) ? wb0[ee] : wb1[ee-4];
                float vc = (ee < 4) ? wc0[ee] : wc1[ee-4];
                float x = bfu2f(pv8[ee]) + bfu2f(qv8[ee]) + d*va + f0*vb + f1*vc;
                float h = (k0 + ee < H1) ? siluf(x) : 0.f;
                union {float f; unsigned u;} cv; cv.f = h;
                unsigned hib = cv.u & 0xFFFF0000u;
                hv[ee] = (ushort_t)(hib >> 16);
                union {unsigned u; float f;} hf; hf.u = hib;
                union {float f; unsigned u;} lw; lw.f = h - hf.f;
                lv[ee] = (ushort_t)(lw.u >> 16);
            }
        }
        bf16x8 ah = *reinterpret_cast<bf16x8*>(&hv);
        bf16x8 al = *reinterpret_cast<bf16x8*>(&lv);
        const ushort_t* Wk = W2T + k0;
#pragma unroll
        for (int nf = 0; nf < 4; nf++) {
            bf16x8 bfr = *reinterpret_cast<const bf16x8*>(Wk + (size_t)(nf*16 + m16)*KPAD);
            acc[nf] = __builtin_amdgcn_mfma_f32_16x16x32_bf16(ah, bfr, acc[nf], 0, 0, 0);
            acc[nf] = __builtin_amdgcn_mfma_f32_16x16x32_bf16(al, bfr, acc[nf], 0, 0, 0);
        }
    }

#pragma unroll
    for (int nf = 0; nf < 4; nf++) {
        const int n = nf*16 + m16;
        const float bias = eb2[n];
#pragma unroll
        for (int r = 0; r < 4; r++) {
            int pe = wbase + kg*4 + r;
            if (pe < np) {
                int rr = pairs[pe] >> 16;
                float m = siluf(acc[nf][r] + bias);
                atomicAdd(&macc[(size_t)rr*MD + n], m);
            }
        }
    }
}

// ================= stage4: fused node1+node2 (hidden in LDS) + feat copy =================
// Node role: block = 32 rows. GEMM1 (K=320 incl. macc ext) -> silu -> LDS hi/lo ->
// GEMM2 (K=512) -> out_node. Hidden never touches HBM.
__global__ __launch_bounds__(256)
void stage4(const ushort_t* __restrict__ Aeph, const ushort_t* __restrict__ Aepl,
            const ushort_t* __restrict__ W1h, const ushort_t* __restrict__ W1l,
            const float* __restrict__ macc, const float* __restrict__ nb1,
            const ushort_t* __restrict__ W2h, const ushort_t* __restrict__ W2l,
            const float* __restrict__ nb2, const float* __restrict__ emb,
            const float* __restrict__ feat,
            float* __restrict__ out_node, float* __restrict__ out_feat)
{
    if (blockIdx.x >= N4_BLKS) {
        // feat copy role (float4)
        int t = (blockIdx.x - N4_BLKS)*256 + threadIdx.x;
        if (t < FCOPY4) ((float4*)out_feat)[t] = ((const float4*)feat)[t];
        return;
    }
    __shared__ ushort_t hidh[32][520];   // 520 stride: <=2-way bank aliasing on b128 reads
    __shared__ ushort_t hidl[32][520];
    const int lane = threadIdx.x & 63, w = threadIdx.x >> 6;
    const int m16 = lane & 15, kg = lane >> 4;
    const int rowBase = blockIdx.x * 32;

    // ---- GEMM1: hidden[32][512], wave w covers cols w*128 .. w*128+127 ----
#pragma unroll
    for (int ct = 0; ct < 2; ct++) {
        const int colBase = w*128 + ct*64;
        f32x4 acc[2][4] = {{{0,0,0,0},{0,0,0,0},{0,0,0,0},{0,0,0,0}},
                           {{0,0,0,0},{0,0,0,0},{0,0,0,0},{0,0,0,0}}};
        mfma_tile2<DIMC>(Aeph + (size_t)rowBase*KN1, Aepl + (size_t)rowBase*KN1, KN1,
                         W1h + (size_t)colBase*KN1, W1l + (size_t)colBase*KN1, KN1, lane, acc);
        // K extension 256..320 from macc f32, fragments built in registers
        {
            const float* mr0 = macc + (size_t)(rowBase + m16)*MD;
            const float* mr1 = macc + (size_t)(rowBase + 16 + m16)*MD;
            const ushort_t* brh_b = W1h + ((size_t)colBase + m16)*KN1 + DIMC + kg*8;
            const ushort_t* brl_b = W1l + ((size_t)colBase + m16)*KN1 + DIMC + kg*8;
#pragma unroll
            for (int ks = 0; ks < 2; ks++) {
                int kk = ks*32 + kg*8;
                f32x4 va = *reinterpret_cast<const f32x4*>(mr0 + kk);
                f32x4 vb = *reinterpret_cast<const f32x4*>(mr0 + kk + 4);
                f32x4 vc = *reinterpret_cast<const f32x4*>(mr1 + kk);
                f32x4 vd = *reinterpret_cast<const f32x4*>(mr1 + kk + 4);
                u16x8 h0, l0, h1, l1;
#pragma unroll
                for (int e = 0; e < 8; e++) {
                    ushort_t hi, lo;
                    split_hilo((e < 4) ? va[e] : vb[e-4], hi, lo); h0[e] = hi; l0[e] = lo;
                    split_hilo((e < 4) ? vc[e] : vd[e-4], hi, lo); h1[e] = hi; l1[e] = lo;
                }
                bf16x8 a0h = *reinterpret_cast<bf16x8*>(&h0);
                bf16x8 a0l = *reinterpret_cast<bf16x8*>(&l0);
                bf16x8 a1h = *reinterpret_cast<bf16x8*>(&h1);
                bf16x8 a1l = *reinterpret_cast<bf16x8*>(&l1);
#pragma unroll
                for (int nf = 0; nf < 4; nf++) {
                    bf16x8 bh = *reinterpret_cast<const bf16x8*>(brh_b + (size_t)(nf*16)*KN1 + ks*32);
                    bf16x8 bl = *reinterpret_cast<const bf16x8*>(brl_b + (size_t)(nf*16)*KN1 + ks*32);
                    acc[0][nf] = __builtin_amdgcn_mfma_f32_16x16x32_bf16(a0h, bh, acc[0][nf], 0, 0, 0);
                    acc[0][nf] = __builtin_amdgcn_mfma_f32_16x16x32_bf16(a0h, bl, acc[0][nf], 0, 0, 0);
                    acc[0][nf] = __builtin_amdgcn_mfma_f32_16x16x32_bf16(a0l, bh, acc[0][nf], 0, 0, 0);
                    acc[1][nf] = __builtin_amdgcn_mfma_f32_16x16x32_bf16(a1h, bh, acc[1][nf], 0, 0, 0);
                    acc[1][nf] = __builtin_amdgcn_mfma_f32_16x16x32_bf16(a1h, bl, acc[1][nf], 0, 0, 0);
                    acc[1][nf] = __builtin_amdgcn_mfma_f32_16x16x32_bf16(a1l, bh, acc[1][nf], 0, 0, 0);
                }
            }
        }
        // silu + bias -> LDS (hi/lo)
#pragma unroll
        for (int tt = 0; tt < 2; tt++) {
#pragma unroll
            for (int nf = 0; nf < 4; nf++) {
#pragma unroll
                for (int r = 0; r < 4; r++) {
                    int lrow = tt*16 + kg*4 + r;
                    int col = colBase + nf*16 + m16;
                    float s = siluf(acc[tt][nf][r] + nb1[col]);
                    ushort_t hi, lo; split_hilo(s, hi, lo);
                    hidh[lrow][col] = hi;
                    hidl[lrow][col] = lo;
                }
            }
        }
    }
    __syncthreads();

    // ---- GEMM2: out[32][w*64 .. w*64+63], K=512 from LDS ----
    f32x4 acc2[2][4] = {{{0,0,0,0},{0,0,0,0},{0,0,0,0},{0,0,0,0}},
                        {{0,0,0,0},{0,0,0,0},{0,0,0,0},{0,0,0,0}}};
    const int colB2 = w*64;
    const ushort_t* b2h = W2h + ((size_t)colB2 + m16)*KN2 + kg*8;
    const ushort_t* b2l = W2l + ((size_t)colB2 + m16)*KN2 + kg*8;
#pragma unroll 4
    for (int ks = 0; ks < KN2/32; ks++) {
        const int k = ks*32 + kg*8;
        bf16x8 a0h = *reinterpret_cast<const bf16x8*>(&hidh[m16][k]);
        bf16x8 a0l = *reinterpret_cast<const bf16x8*>(&hidl[m16][k]);
        bf16x8 a1h = *reinterpret_cast<const bf16x8*>(&hidh[m16+16][k]);
        bf16x8 a1l = *reinterpret_cast<const bf16x8*>(&hidl[m16+16][k]);
#pragma unroll
        for (int nf = 0; nf < 4; nf++) {
            bf16x8 bh = *reinterpret_cast<const bf16x8*>(b2h + (size_t)(nf*16)*KN2 + ks*32);
            bf16x8 bl = *reinterpret_cast<const bf16x8*>(b2l + (size_t)(nf*16)*KN2 + ks*32);
            acc2[0][nf] = __builtin_amdgcn_mfma_f32_16x16x32_bf16(a0h, bh, acc2[0][nf], 0, 0, 0);
            acc2[0][nf] = __builtin_amdgcn_mfma_f32_16x16x32_bf16(a0h, bl, acc2[0][nf], 0, 0, 0);
            acc2[0][nf] = __builtin_amdgcn_mfma_f32_16x16x32_bf16(a0l, bh, acc2[0][nf], 0, 0, 0);
            acc2[1][nf] = __builtin_amdgcn_mfma_f32_16x16x32_bf16(a1h, bh, acc2[1][nf], 0, 0, 0);
            acc2[1][nf] = __builtin_amdgcn_mfma_f32_16x16x32_bf16(a1h, bl, acc2[1][nf], 0, 0, 0);
            acc2[1][nf] = __builtin_amdgcn_mfma_f32_16x16x32_bf16(a1l, bh, acc2[1][nf], 0, 0, 0);
        }
    }
#pragma unroll
    for (int tt = 0; tt < 2; tt++) {
#pragma unroll
        for (int nf = 0; nf < 4; nf++) {
#pragma unroll
            for (int r = 0; r < 4; r++) {
                int row = rowBase + tt*16 + kg*4 + r;
                int col = colB2 + nf*16 + m16;
                size_t o = (size_t)row*DIMC + col;
                out_node[o] = acc2[tt][nf][r] + nb2[col] + emb[o];
            }
        }
    }
}

extern "C" void kernel_launch(void* const* d_in, const int* in_sizes, int n_in,
                              void* d_out, int out_size, void* d_ws, size_t ws_size,
                              hipStream_t stream)
{
    const float* emb   = (const float*)d_in[0];
    const float* coors = (const float*)d_in[1];
    const int*   adj   = (const int*)d_in[2];
    const float* feat  = (const float*)d_in[3];
    const int*   mask  = (const int*)d_in[4];
    const float* eW1   = (const float*)d_in[5];
    const float* eb1   = (const float*)d_in[6];
    const float* eW2   = (const float*)d_in[7];
    const float* eb2   = (const float*)d_in[8];
    const float* nW1   = (const float*)d_in[9];
    const float* nb1   = (const float*)d_in[10];
    const float* nW2   = (const float*)d_in[11];
    const float* nb2   = (const float*)d_in[12];

    float* out       = (float*)d_out;
    float* out_node  = out;               // [4,2048,256]   2,097,152
    float* out_coors = out + 2097152;     // [4,2048,3]        24,576
    float* out_adj   = out + 2121728;     // [4,2048,2048] 16,777,216
    float* out_feat  = out + 18898944;    // [4,2048,2048,2] 33,554,432
    float* out_mask  = out + 52453376;    // [4,2048]           8,192

    char* ws = (char*)d_ws;                          // total used: 31,338,944 B (< 37 MB proven)
    int*      counter = (int*)(ws + 0);              // 256 B
    float*    macc    = (float*)(ws + 256);          // 8192x64 f32 -> ends 2,097,408
    int*      pairs   = (int*)(ws + 2097408);        // 131072 ints -> ends 2,621,696
    ushort_t* Pbuf    = (ushort_t*)(ws + 2621696);   // [8192][1040] bf16 -> ends 19,661,056
    float*    wt4     = (float*)(ws + 19661056);     // [3][1040] f32 -> ends 19,673,536
    ushort_t* NW2T_h  = (ushort_t*)(ws + 19673536);  // [256][512] -> ends 19,935,680
    ushort_t* NW2T_l  = (ushort_t*)(ws + 19935680);  // -> ends 20,197,824
    ushort_t* Aep_h   = (ushort_t*)(ws + 20197824);  // [8192][320] -> ends 25,440,704
    ushort_t* Aep_l   = (ushort_t*)(ws + 25440704);  // -> ends 30,683,584
    ushort_t* W1T_h   = (ushort_t*)(ws + 30683584);  // [512][320] -> ends 31,011,264
    ushort_t* W1T_l   = (ushort_t*)(ws + 31011264);  // -> ends 31,338,944

    // Scratch parked in out_feat region: Wpq consumed by stage2, Qbuf by stage3; the
    // stage4 feat-copy overwrites the region only after both are dead.
    char* scr = (char*)out_feat;
    ushort_t* Wpq_h = (ushort_t*)(scr + 0);          // [2112][256] -> 1,081,344
    ushort_t* Wpq_l = (ushort_t*)(scr + 1081344);    // -> 2,162,688
    ushort_t* Qbuf  = (ushort_t*)(scr + 2162688);    // [8192][1040] -> ends 19,202,048

    // W2T (edge eW2^T bf16 [64][1056]) parked in out_node region; consumed by edge_mfma,
    // fully overwritten afterwards by stage4's node role.
    ushort_t* W2T = (ushort_t*)out_node;

    hipMemsetAsync(counter, 0, 256, stream);

    // stage1: adj + all prep + macc-zero + coors copy
    {
        int extra = (PREP_TOT + MACCZ + COORSZ + 255)/256;
        stage1<<<ADJ_BLKS + extra, 256, 0, stream>>>(adj, mask, coors, eW1, nW1, nW2, eW2, emb,
                                                     out_adj, out_mask, out_coors, pairs, counter,
                                                     Wpq_h, Wpq_l, W1T_h, W1T_l, NW2T_h, NW2T_l,
                                                     W2T, wt4, Aep_h, Aep_l, macc);
    }

    // stage2: P/Q GEMM (MFMA), eb1 folded into P
    gemm_pq_mfma<<<dim3(NROWS/128, NPQP/64), 256, 0, stream>>>(Aep_h, Aep_l, Wpq_h, Wpq_l, eb1, Pbuf, Qbuf);

    // stage3: edge phase
    edge_mfma<<<2048, 256, 0, stream>>>(pairs, counter, Pbuf, Qbuf, coors, feat,
                                        wt4, W2T, eb2, macc);

    // stage4: fused node1+node2 (hidden in LDS) + feat passthrough copy
    stage4<<<N4_BLKS + FCOPY4/256, 256, 0, stream>>>(Aep_h, Aep_l, W1T_h, W1T_l, macc, nb1,
                                                     NW2T_h, NW2T_l, nb2, emb, feat,
                                                     out_node, out_feat);
}